// Round 7
// baseline (191.043 us; speedup 1.0000x reference)
//
#include <hip/hip_runtime.h>
#include <hip/hip_cooperative_groups.h>

namespace cg = cooperative_groups;

// HausdorffDTLoss: exact separable EDT (fg & bg) per image, then
// mean((pred-target)^2 * (pred_dt^2 + target_dt^2)).
// Envelope identity: g[i] = min_j f[j]+(i-j)^2 = i^2 + min_j (h[j]-2ij),
// h[j]=f[j]+j^2. All intermediates are integers, |val| < 2^17 -> u16 storage,
// fp32 math exact (R1-R15: absmax 0.0).
// R12 windowing: scan only |i-j| <= W, W = ceil(sqrt(max f over outputs)) --
// exact for any input (j=i in-window; outside candidates >= f(i) >= g(i)).
//
// R16. R15: 190us (zy 82 -- 2-deep ring REGRESSED vs R14's 77; reverted).
// Kernel-sum ~153us vs total 182-190 -> ~30us is inter-kernel launch/gap
// overhead (3 launches x ~10us). Fix: ONE cooperative kernel
// {zero; grid.sync; zy; grid.sync; xloss} at the shared launch shape
// (1024 x 512, ~36KB LDS, 4 blocks/CU). Guarded: occupancy query + launch
// error both fall back to the proven 3-kernel path (worst case = R14 perf).
// Also: xloss stage writes 2 u32 LDS words instead of 4 u16.

constexpr int BIGI = 49153;      // 3*128^2+1, matches reference BIG exactly
constexpr int NVOX = 4194304;    // voxels per tensor (2 samples x 128^3)
constexpr int STZ  = 129;        // zy dword row stride: 129%32=1 -> 2-way max (free)
constexpr int STX  = 65;         // xloss dword row stride: 65%32=1 -> same property
constexpr int LDSW = 512 + 65 * STZ;   // u32 words: bm(256 u64 = 512) + hz(8385)

// Windowed pair-packed lower-envelope into acc[16] at outputs i0..i0+15.
// p = column c of a [65*stride] u32 LDS array of packed u16 h-values
// (row 64 = slack for the 1-ahead prefetch). R14 proven form.
__device__ __forceinline__ void envelope_win(const unsigned int* __restrict__ p,
                                             const int stride, const float i0f,
                                             const int qlo, const int qhi,
                                             float acc[16]) {
    unsigned int vc = p[qlo * stride];
    float jm2 = -4.0f * (float)qlo;            // -2*(2q)
    for (int q = qlo; q <= qhi; ++q) {
        unsigned int vn = p[(q + 1) * stride]; // 1-pair prefetch (slack row)
        float h0 = (float)(vc & 0xffffu);      // j = 2q
        float h1 = (float)(vc >> 16);          // j = 2q+1
        float jb = jm2 - 2.0f;
        float c0 = fmaf(jm2, i0f, h0);         // candidate at i = i0
        float c1 = fmaf(jb,  i0f, h1);
#pragma unroll
        for (int k = 0; k < 16; ++k) {
            acc[k] = fminf(acc[k], fminf(c0, c1));
            c0 += jm2; c1 += jb;               // exact: integers < 2^17
        }
        jm2 -= 4.0f;
        vc = vn;
    }
}

// Wave-uniform window W from the wave's 16 output rows' f-values (pair-packed
// layout; f = h - i^2), wave-maxed. Guarantees W*W >= fmax.
__device__ __forceinline__ int window_of(const unsigned int* __restrict__ p,
                                         const int stride, const int i0) {
    int fmx = 0;
#pragma unroll
    for (int m = 0; m < 8; ++m) {
        unsigned int v = p[((i0 >> 1) + m) * stride];
        int y0 = i0 + 2 * m, y1 = y0 + 1;
        int f0 = (int)(v & 0xffffu) - y0 * y0;
        int f1 = (int)(v >> 16) - y1 * y1;
        fmx = max(fmx, max(f0, f1));
    }
#pragma unroll
    for (int off = 32; off; off >>= 1) fmx = max(fmx, __shfl_xor(fmx, off));
    int W = (int)sqrtf((float)fmx);            // fmx <= 49153, exact in fp32
    W += (W * W < fmx);
    W += (W * W < fmx);                        // guarantees W*W >= fmx
    return W;
}

// ---- zy phase body: binarize + bitmask z-EDT + windowed y-envelope ----
// One (b,x) slab, one image, one polarity per block t. Stores g + x^2 (u16).
__device__ __forceinline__ void zy_body(const float* __restrict__ pred,
                                        const float* __restrict__ tgt,
                                        unsigned short* __restrict__ ws,
                                        int* __restrict__ flags,
                                        unsigned int* lds, const int t) {
    unsigned long long* bm = (unsigned long long*)lds;   // 256 u64 site masks
    unsigned int* hz = lds + 512;                        // 65*STZ packed pairs
    const int pol = t & 1;                         // 0: fg EDT (sites=~fg), 1: bg
    const int img = (t >> 1) & 1;
    const int s   = t >> 2;                        // 0..255: b(2) x x(128)
    const int b   = s >> 7;
    const int x   = s & 127;
    const int sb  = (b * 128 + x) * 16384;         // + y*128 + z
    const int tid = threadIdx.x;
    const float* im = img ? tgt : pred;

    // stage: coalesced read -> per-wave ballot -> site bitmasks
    bool anyfg = false;
#pragma unroll
    for (int k = 0; k < 32; ++k) {
        int l = tid + k * 512;
        float v = im[sb + l];
        bool fg = v > 0.5f;
        anyfg |= fg;
        bool site = pol ? fg : !fg;
        unsigned long long bal = __ballot(site);
        if ((tid & 63) == 0) bm[l >> 6] = bal;     // l>>6 uniform per wave
    }
    if (!pol && __ballot(anyfg) != 0ULL && (tid & 63) == 0)
        atomicOr(flags + img * 2 + b, 1);
    __syncthreads();

    // parallel z-EDT: per-voxel nearest-site distance from the masks
    unsigned short* hu = (unsigned short*)hz;
    const int z = tid & 127;                       // fixed per thread, uniform/wave
#pragma unroll
    for (int k = 0; k < 32; ++k) {
        int y = (tid >> 7) + k * 4;
        unsigned long long m0 = bm[2 * y], m1 = bm[2 * y + 1];
        int d;
        if (z < 64) {
            unsigned long long lm = m0 << (63 - z);
            unsigned long long rm = m0 >> z;
            int dfwd = lm ? __builtin_clzll(lm) : 999;
            int db0  = rm ? __builtin_ctzll(rm) : 999;
            int db1  = (m1 ? __builtin_ctzll(m1) : 999) + (64 - z);
            d = min(dfwd, min(db0, db1));
        } else {
            int zz = z - 64;
            unsigned long long lm = m1 << (63 - zz);
            unsigned long long rm = m1 >> zz;
            int df1 = lm ? __builtin_clzll(lm) : 999;
            int df0 = (m0 ? __builtin_clzll(m0) : 999) + zz + 1;
            int dbw = rm ? __builtin_ctzll(rm) : 999;
            d = min(min(df1, df0), dbw);
        }
        int f = (d <= 127) ? d * d : BIGI;         // empty line -> BIG (exact)
        hu[((y >> 1) * STZ) * 2 + (y & 1) + 2 * z] = (unsigned short)(f + y * y);
    }
    __syncthreads();

    // y-envelope: c = z column, 4 groups x 2 rounds; store g + x^2 (u16)
    unsigned short* outv = ws + (size_t)(img * 2 + pol) * NVOX + sb;
    const int c = tid & 127;
    const int xsq = x * x;
#pragma clang loop unroll(disable)
    for (int r = 0; r < 2; ++r) {                  // one acc[16] live at a time
        const int i0 = (tid >> 7) * 16 + r * 64;   // wave-uniform (tid>>7)
        const float i0f = (float)i0;
        const int W = window_of(hz + c, STZ, i0);
        const int qlo = __builtin_amdgcn_readfirstlane(max(0, (i0 - W) >> 1));
        const int qhi = __builtin_amdgcn_readfirstlane(min(63, (i0 + 15 + W) >> 1));
        float acc[16];
#pragma unroll
        for (int k = 0; k < 16; ++k) acc[k] = 3.0e38f;
        envelope_win(hz + c, STZ, i0f, qlo, qhi, acc);
#pragma unroll
        for (int k = 0; k < 16; ++k) {             // g + x^2 <= 65282: u16
            float iif = i0f + (float)k;
            outv[(i0 + k) * 128 + c] =
                (unsigned short)((unsigned int)fmaf(iif, iif, acc[k]) + xsq);
        }
    }
}

// ---- xloss phase body: fused dual-polarity x-envelope + loss partial ----
// 64-col tile per block t; LDS word [j][c] = hA | hB<<16; one barrier;
// i0=(tid>>6)*16 wave-uniform; 1-ahead scan ring (2-deep regressed in R15).
__device__ __forceinline__ void xloss_body(const float* __restrict__ pred,
                                           const float* __restrict__ tgt,
                                           const unsigned short* __restrict__ ws,
                                           const int* __restrict__ flags,
                                           float* __restrict__ out,
                                           unsigned int* hx, float* red,
                                           const int t) {
    const int img  = t & 1;                    // adjacent blocks share pred/tgt
    const int b    = (t >> 1) & 1;
    const int q0   = (t >> 2) * 64;            // (y,z) tile base, 0..16320
    const int base = b * 2097152 + q0;         // + x*16384 + c
    const int tid  = threadIdx.x;
    const int c    = tid & 63;
    const int i0   = (tid >> 6) * 16;          // wave-uniform (64 lanes = 64 cols)
    const float i0f = (float)i0;
    const unsigned short* A16 = ws + (size_t)(img * 2) * NVOX;
    const unsigned int* A32 = (const unsigned int*)(A16 + base);       // base even
    const unsigned int* B32 = (const unsigned int*)(A16 + NVOX + base);

    // stage BOTH volumes, u32 in AND out: word[j][c] = hA | hB<<16
#pragma unroll
    for (int k = 0; k < 8; ++k) {
        int l = tid + k * 512;                 // 0..4095
        int j = l >> 5, cp = l & 31;           // row j, u32 col-pair (c=2cp,2cp+1)
        unsigned int va = A32[j * 8192 + cp];
        unsigned int vb = B32[j * 8192 + cp];
        int w0 = j * STX + 2 * cp;
        hx[w0]     = (va & 0xffffu) | (vb << 16);          // col 2cp
        hx[w0 + 1] = (va >> 16)    | (vb & 0xffff0000u);   // col 2cp+1
    }
    __syncthreads();

    // single window over both polarities (superset window = exact)
    const unsigned int* p = hx + c;
    int fmx = 0;
#pragma unroll
    for (int m = 0; m < 16; ++m) {
        int j = i0 + m;
        unsigned int w = p[j * STX];
        int h2 = max((int)(w & 0xffffu), (int)(w >> 16));
        fmx = max(fmx, h2 - j * j);            // f = h - j^2 >= 0
    }
#pragma unroll
    for (int off = 32; off; off >>= 1) fmx = max(fmx, __shfl_xor(fmx, off));
    int W = (int)sqrtf((float)fmx);
    W += (W * W < fmx);
    W += (W * W < fmx);                        // W*W >= fmx
    const int jlo = __builtin_amdgcn_readfirstlane(max(0, i0 - W));
    const int jhi = __builtin_amdgcn_readfirstlane(min(127, i0 + 15 + W));

    // fused scan: accA (pol0) + accB (pol1) in one pass, 1-ahead ring
    float accA[16], accB[16];
#pragma unroll
    for (int k = 0; k < 16; ++k) { accA[k] = 3.0e38f; accB[k] = 3.0e38f; }
    unsigned int vc = p[jlo * STX];
    float jm = -2.0f * (float)jlo;
    for (int j = jlo; j <= jhi; ++j) {
        unsigned int vn = p[(j + 1) * STX];    // row 128 slack exists
        float hA = (float)(vc & 0xffffu);
        float hB = (float)(vc >> 16);
        float cA = fmaf(jm, i0f, hA);          // candidate at i = i0
        float cB = fmaf(jm, i0f, hB);
#pragma unroll
        for (int k = 0; k < 16; ++k) {
            accA[k] = fminf(accA[k], cA);
            accB[k] = fminf(accB[k], cB);
            cA += jm; cB += jm;                // exact: integers < 2^17
        }
        jm -= 2.0f;
        vc = vn;
    }

    // loss partial: (p-t)^2 * (sqrt(gA)+sqrt(gB))^2 * guard
    // (sqrt-then-square kept: reference computes (sqrt g)**2, bit-compat)
    float s = 0.0f;
#pragma unroll
    for (int k = 0; k < 16; ++k) {
        float iif = i0f + (float)k;
        float gA = fmaf(iif, iif, accA[k]);
        float gB = fmaf(iif, iif, accB[k]);
        int v = base + (i0 + k) * 16384 + c;   // 256B contiguous per wave
        float d = pred[v] - tgt[v];
        float fld = sqrtf(gA) + sqrtf(gB);
        s += d * d * fld * fld;
    }
    if (!flags[img * 2 + b]) s = 0.0f;
#pragma unroll
    for (int off = 32; off > 0; off >>= 1) s += __shfl_down(s, off);
    if ((tid & 63) == 0) red[tid >> 6] = s;
    __syncthreads();
    if (tid == 0) {
        float tot = 0.0f;
#pragma unroll
        for (int w = 0; w < 8; ++w) tot += red[w];
        atomicAdd(out, tot * (1.0f / 4194304.0f));
    }
}

// ---- fused cooperative kernel: zero -> zy -> xloss, two grid syncs ----
__global__ __launch_bounds__(512) void fused_kernel(const float* __restrict__ pred,
                                                    const float* __restrict__ tgt,
                                                    unsigned short* __restrict__ ws,
                                                    int* __restrict__ flags,
                                                    float* __restrict__ out) {
    __shared__ __align__(16) unsigned int lds[LDSW];   // 35.6KB, 4 blocks/CU
    __shared__ float red[8];
    const int t = blockIdx.x;
    if (t == 0 && threadIdx.x < 5) {
        if (threadIdx.x == 0) out[0] = 0.0f;
        else flags[threadIdx.x - 1] = 0;
    }
    cg::this_grid().sync();                    // zero visible to all atomicOr
    zy_body(pred, tgt, ws, flags, lds, t);
    cg::this_grid().sync();                    // ws + flags complete
    xloss_body(pred, tgt, ws, flags, out, lds, red, t);
}

// ---- fallback path: the proven 3-kernel pipeline ----
__global__ void zero_kernel(float* out, int* flags) {
    out[0] = 0.0f;
    flags[0] = 0; flags[1] = 0; flags[2] = 0; flags[3] = 0;
}

__global__ __launch_bounds__(512) void zy_kernel(const float* __restrict__ pred,
                                                 const float* __restrict__ tgt,
                                                 unsigned short* __restrict__ ws,
                                                 int* __restrict__ flags) {
    __shared__ __align__(16) unsigned int lds[LDSW];
    zy_body(pred, tgt, ws, flags, lds, blockIdx.x);
}

__global__ __launch_bounds__(512) void xloss_kernel(const float* __restrict__ pred,
                                                    const float* __restrict__ tgt,
                                                    const unsigned short* __restrict__ ws,
                                                    const int* __restrict__ flags,
                                                    float* __restrict__ out) {
    __shared__ __align__(16) unsigned int lds[LDSW];
    __shared__ float red[8];
    xloss_body(pred, tgt, ws, flags, out, lds, red, blockIdx.x);
}

extern "C" void kernel_launch(void* const* d_in, const int* in_sizes, int n_in,
                              void* d_out, int out_size, void* d_ws, size_t ws_size,
                              hipStream_t stream) {
    const float* pred = (const float*)d_in[0];
    const float* tgt  = (const float*)d_in[1];
    float* out = (float*)d_out;
    unsigned short* ws16 = (unsigned short*)d_ws;  // 4 u16 volumes = 33.6 MB
    int* flags = (int*)(ws16 + 4 * (size_t)NVOX);  // [img0_b0, img0_b1, img1_b0, img1_b1]

    // Cooperative fusion requires 1024 co-resident blocks (4/CU x 256 CU).
    int cap = 0;
    hipError_t qe = hipOccupancyMaxActiveBlocksPerMultiprocessor(
        &cap, reinterpret_cast<const void*>(fused_kernel), 512, 0);
    bool coop = (qe == hipSuccess && cap >= 4);
    if (coop) {
        void* args[] = {(void*)&pred, (void*)&tgt, (void*)&ws16,
                        (void*)&flags, (void*)&out};
        if (hipLaunchCooperativeKernel(reinterpret_cast<const void*>(fused_kernel),
                                       dim3(1024), dim3(512), args, 0, stream)
            != hipSuccess)
            coop = false;                      // e.g. not capturable -> fallback
    }
    if (!coop) {
        zero_kernel<<<1, 1, 0, stream>>>(out, flags);
        zy_kernel<<<dim3(1024), 512, 0, stream>>>(pred, tgt, ws16, flags);
        xloss_kernel<<<dim3(1024), 512, 0, stream>>>(pred, tgt, ws16, flags, out);
    }
}

// Round 8
// 150.810 us; speedup vs baseline: 1.2668x; 1.2668x over previous
//
#include <hip/hip_runtime.h>

// HausdorffDTLoss: exact separable EDT (fg & bg) per image, then
// mean((pred-target)^2 * (pred_dt^2 + target_dt^2)).
// Envelope identity: g[i] = min_j f[j]+(i-j)^2 = i^2 + min_j (h[j]-2ij),
// h[j]=f[j]+j^2. All intermediates are integers, |val| < 2^17 -> u16 storage,
// fp32 math exact (R1-R16: absmax 0.0).
// R12 windowing: scan only |i-j| <= W, W = ceil(sqrt(max f over outputs)) --
// exact for any input (j=i in-window; outside candidates >= f(i) >= g(i)).
//
// R17. R16's cooperative launch never ran (fallback path in profile) -- coop
// is not usable here. Post-mortem correction: zy 77->85 regression was losing
// R14's two-phase stage (R15 changed stage AND ring together; R16 isolated
// the ring). This round:
//  - zy: restore two-phase stage (batch 32 loads -> ballots). Proven 77us.
//  - flags/zero ELIMINATED: bg-EDT is uniformly BIGI iff sample has no fg
//    (else <= 3*127^2 = 48387), so xloss derives the guard from its own
//    window pass (fmxB >= BIGI). All-fg case: fB=0 -> keep (matches ref).
//    out zeroed by hipMemsetAsync (graph-capturable). 3 dispatches -> 2.
//  - xloss: pred/tgt scattered loads hoisted BEFORE window+scan (latency
//    hides under ~3000cyc of envelope work), dv[16] in registers.

constexpr int BIGI = 49153;      // 3*128^2+1, matches reference BIG exactly
constexpr int NVOX = 4194304;    // voxels per tensor (2 samples x 128^3)
constexpr int STZ  = 129;        // zy dword row stride: 129%32=1 -> 2-way max (free)
constexpr int STX  = 65;         // xloss dword row stride: 65%32=1 -> same property

// Windowed pair-packed lower-envelope into acc[16] at outputs i0..i0+15.
// p = column c of a [65*stride] u32 LDS array of packed u16 h-values
// (row 64 = slack for the 1-ahead prefetch). R14 proven form.
__device__ __forceinline__ void envelope_win(const unsigned int* __restrict__ p,
                                             const int stride, const float i0f,
                                             const int qlo, const int qhi,
                                             float acc[16]) {
    unsigned int vc = p[qlo * stride];
    float jm2 = -4.0f * (float)qlo;            // -2*(2q)
    for (int q = qlo; q <= qhi; ++q) {
        unsigned int vn = p[(q + 1) * stride]; // 1-pair prefetch (slack row)
        float h0 = (float)(vc & 0xffffu);      // j = 2q
        float h1 = (float)(vc >> 16);          // j = 2q+1
        float jb = jm2 - 2.0f;
        float c0 = fmaf(jm2, i0f, h0);         // candidate at i = i0
        float c1 = fmaf(jb,  i0f, h1);
#pragma unroll
        for (int k = 0; k < 16; ++k) {
            acc[k] = fminf(acc[k], fminf(c0, c1));
            c0 += jm2; c1 += jb;               // exact: integers < 2^17
        }
        jm2 -= 4.0f;
        vc = vn;
    }
}

// Wave-uniform window W from the wave's 16 output rows' f-values (pair-packed
// layout; f = h - i^2), wave-maxed. Guarantees W*W >= fmax.
__device__ __forceinline__ int window_of(const unsigned int* __restrict__ p,
                                         const int stride, const int i0) {
    int fmx = 0;
#pragma unroll
    for (int m = 0; m < 8; ++m) {
        unsigned int v = p[((i0 >> 1) + m) * stride];
        int y0 = i0 + 2 * m, y1 = y0 + 1;
        int f0 = (int)(v & 0xffffu) - y0 * y0;
        int f1 = (int)(v >> 16) - y1 * y1;
        fmx = max(fmx, max(f0, f1));
    }
#pragma unroll
    for (int off = 32; off; off >>= 1) fmx = max(fmx, __shfl_xor(fmx, off));
    int W = (int)sqrtf((float)fmx);            // fmx <= 49153, exact in fp32
    W += (W * W < fmx);
    W += (W * W < fmx);                        // guarantees W*W >= fmx
    return W;
}

// Fused binarize + parallel bitmask z-EDT + windowed y-envelope for one (b,x)
// slab of one image, one polarity. 512 thr, 35.8KB LDS, 4 blocks/CU
// (thread-capped). Grid 1024 = (pol, img, b*x). Stores g + x^2 (u16).
__global__ __launch_bounds__(512) void zy_kernel(const float* __restrict__ pred,
                                                 const float* __restrict__ tgt,
                                                 unsigned short* __restrict__ ws) {
    __shared__ unsigned int hz[65 * STZ];          // packed u16 pairs: (y-pair, z)
    __shared__ unsigned long long bm[256];         // site bitmasks: [y][z-half]
    const int t   = blockIdx.x;
    const int pol = t & 1;                         // 0: fg EDT (sites=~fg), 1: bg
    const int img = (t >> 1) & 1;
    const int s   = t >> 2;                        // 0..255: b(2) x x(128)
    const int b   = s >> 7;
    const int x   = s & 127;
    const int sb  = (b * 128 + x) * 16384;         // + y*128 + z
    const int tid = threadIdx.x;
    const float* im = img ? tgt : pred;

    // ---- stage phase 1: batch ALL 32 slab loads (R14 proven two-phase) ----
    float vreg[32];
#pragma unroll
    for (int k = 0; k < 32; ++k) vreg[k] = im[sb + tid + k * 512];

    // ---- stage phase 2: ballots -> site bitmasks ----
#pragma unroll
    for (int k = 0; k < 32; ++k) {
        bool fg = vreg[k] > 0.5f;
        bool site = pol ? fg : !fg;
        unsigned long long bal = __ballot(site);
        if ((tid & 63) == 0) bm[(tid + k * 512) >> 6] = bal; // uniform per wave
    }
    __syncthreads();

    // ---- parallel z-EDT: per-voxel nearest-site distance from the masks ----
    unsigned short* hu = (unsigned short*)hz;
    const int z = tid & 127;                       // fixed per thread, uniform/wave
#pragma unroll
    for (int k = 0; k < 32; ++k) {
        int y = (tid >> 7) + k * 4;
        unsigned long long m0 = bm[2 * y], m1 = bm[2 * y + 1];
        int d;
        if (z < 64) {
            unsigned long long lm = m0 << (63 - z);
            unsigned long long rm = m0 >> z;
            int dfwd = lm ? __builtin_clzll(lm) : 999;
            int db0  = rm ? __builtin_ctzll(rm) : 999;
            int db1  = (m1 ? __builtin_ctzll(m1) : 999) + (64 - z);
            d = min(dfwd, min(db0, db1));
        } else {
            int zz = z - 64;
            unsigned long long lm = m1 << (63 - zz);
            unsigned long long rm = m1 >> zz;
            int df1 = lm ? __builtin_clzll(lm) : 999;
            int df0 = (m0 ? __builtin_clzll(m0) : 999) + zz + 1;
            int dbw = rm ? __builtin_ctzll(rm) : 999;
            d = min(min(df1, df0), dbw);
        }
        int f = (d <= 127) ? d * d : BIGI;         // empty line -> BIG (exact)
        hu[((y >> 1) * STZ) * 2 + (y & 1) + 2 * z] = (unsigned short)(f + y * y);
    }
    __syncthreads();

    // ---- y-envelope: c = z column, 4 groups x 2 rounds; store g + x^2 ----
    unsigned short* outv = ws + (size_t)(img * 2 + pol) * NVOX + sb;
    const int c = tid & 127;
    const int xsq = x * x;
#pragma clang loop unroll(disable)
    for (int r = 0; r < 2; ++r) {                  // one acc[16] live at a time
        const int i0 = (tid >> 7) * 16 + r * 64;   // wave-uniform (tid>>7)
        const float i0f = (float)i0;
        const int W = window_of(hz + c, STZ, i0);
        const int qlo = __builtin_amdgcn_readfirstlane(max(0, (i0 - W) >> 1));
        const int qhi = __builtin_amdgcn_readfirstlane(min(63, (i0 + 15 + W) >> 1));
        float acc[16];
#pragma unroll
        for (int k = 0; k < 16; ++k) acc[k] = 3.0e38f;
        envelope_win(hz + c, STZ, i0f, qlo, qhi, acc);
#pragma unroll
        for (int k = 0; k < 16; ++k) {             // g + x^2 <= 65282: u16
            float iif = i0f + (float)k;
            outv[(i0 + k) * 128 + c] =
                (unsigned short)((unsigned int)fmaf(iif, iif, acc[k]) + xsq);
        }
    }
}

// Fused dual-polarity x-envelope + loss partial. 64-col tiles, 512 thr,
// 33.6KB LDS, 4 blocks/CU. Grid 1024 = (img, b, 256 tiles).
// LDS word [j][c] = hA | hB<<16: both polarity volumes in ONE scan;
// i0=(tid>>6)*16 wave-uniform. Guard derived from fmxB (no flags array).
__global__ __launch_bounds__(512) void xloss_kernel(const float* __restrict__ pred,
                                                    const float* __restrict__ tgt,
                                                    const unsigned short* __restrict__ ws,
                                                    float* __restrict__ out) {
    __shared__ unsigned int hx[129 * STX];     // rows 0..127 data + 1 slack
    __shared__ float red[8];
    const int t    = blockIdx.x;
    const int img  = t & 1;                    // adjacent blocks share pred/tgt
    const int b    = (t >> 1) & 1;
    const int q0   = (t >> 2) * 64;            // (y,z) tile base, 0..16320
    const int base = b * 2097152 + q0;         // + x*16384 + c
    const int tid  = threadIdx.x;
    const int c    = tid & 63;
    const int i0   = (tid >> 6) * 16;          // wave-uniform (64 lanes = 64 cols)
    const float i0f = (float)i0;
    const unsigned short* A16 = ws + (size_t)(img * 2) * NVOX;
    const unsigned int* A32 = (const unsigned int*)(A16 + base);       // base even
    const unsigned int* B32 = (const unsigned int*)(A16 + NVOX + base);

    // ---- hoisted scattered pred/tgt loads: latency hides under the scan ----
    float dv[16];
#pragma unroll
    for (int k = 0; k < 16; ++k) {
        int v = base + (i0 + k) * 16384 + c;   // 256B contiguous per wave
        dv[k] = pred[v] - tgt[v];
    }

    // ---- stage BOTH volumes, u32 in AND out: word[j][c] = hA | hB<<16 ----
#pragma unroll
    for (int k = 0; k < 8; ++k) {
        int l = tid + k * 512;                 // 0..4095
        int j = l >> 5, cp = l & 31;           // row j, u32 col-pair (c=2cp,2cp+1)
        unsigned int va = A32[j * 8192 + cp];
        unsigned int vb = B32[j * 8192 + cp];
        int w0 = j * STX + 2 * cp;
        hx[w0]     = (va & 0xffffu) | (vb << 16);          // col 2cp
        hx[w0 + 1] = (va >> 16)    | (vb & 0xffff0000u);   // col 2cp+1
    }
    __syncthreads();

    // ---- window over both polarities + no-fg guard from fmxB ----
    const unsigned int* p = hx + c;
    int fmxA = 0, fmxB = 0;
#pragma unroll
    for (int m = 0; m < 16; ++m) {
        int j = i0 + m;
        unsigned int w = p[j * STX];
        fmxA = max(fmxA, (int)(w & 0xffffu) - j * j);  // f = h - j^2 >= 0
        fmxB = max(fmxB, (int)(w >> 16) - j * j);
    }
    int fmx = max(fmxA, fmxB);
#pragma unroll
    for (int off = 32; off; off >>= 1) {
        fmx  = max(fmx,  __shfl_xor(fmx,  off));
        fmxB = max(fmxB, __shfl_xor(fmxB, off));
    }
    int W = (int)sqrtf((float)fmx);
    W += (W * W < fmx);
    W += (W * W < fmx);                        // W*W >= fmx
    const int jlo = __builtin_amdgcn_readfirstlane(max(0, i0 - W));
    const int jhi = __builtin_amdgcn_readfirstlane(min(127, i0 + 15 + W));
    // bg-EDT f == BIGI uniformly iff sample has no fg (else <= 48387 < BIGI)
    const bool nofg = (fmxB >= BIGI);

    // ---- fused scan: accA (pol0) + accB (pol1) in one pass, 1-ahead ----
    float accA[16], accB[16];
#pragma unroll
    for (int k = 0; k < 16; ++k) { accA[k] = 3.0e38f; accB[k] = 3.0e38f; }
    unsigned int vc = p[jlo * STX];
    float jm = -2.0f * (float)jlo;
    for (int j = jlo; j <= jhi; ++j) {
        unsigned int vn = p[(j + 1) * STX];    // row 128 slack exists
        float hA = (float)(vc & 0xffffu);
        float hB = (float)(vc >> 16);
        float cA = fmaf(jm, i0f, hA);          // candidate at i = i0
        float cB = fmaf(jm, i0f, hB);
#pragma unroll
        for (int k = 0; k < 16; ++k) {
            accA[k] = fminf(accA[k], cA);
            accB[k] = fminf(accB[k], cB);
            cA += jm; cB += jm;                // exact: integers < 2^17
        }
        jm -= 2.0f;
        vc = vn;
    }

    // ---- loss partial: (p-t)^2 * (sqrt(gA)+sqrt(gB))^2 * guard ----
    // (sqrt-then-square kept: reference computes (sqrt g)**2, bit-compat)
    float s = 0.0f;
#pragma unroll
    for (int k = 0; k < 16; ++k) {
        float iif = i0f + (float)k;
        float gA = fmaf(iif, iif, accA[k]);
        float gB = fmaf(iif, iif, accB[k]);
        float d = dv[k];
        float fld = sqrtf(gA) + sqrtf(gB);
        s += d * d * fld * fld;
    }
    if (nofg) s = 0.0f;
#pragma unroll
    for (int off = 32; off > 0; off >>= 1) s += __shfl_down(s, off);
    if ((tid & 63) == 0) red[tid >> 6] = s;
    __syncthreads();
    if (tid == 0) {
        float tot = 0.0f;
#pragma unroll
        for (int w = 0; w < 8; ++w) tot += red[w];
        atomicAdd(out, tot * (1.0f / 4194304.0f));
    }
}

extern "C" void kernel_launch(void* const* d_in, const int* in_sizes, int n_in,
                              void* d_out, int out_size, void* d_ws, size_t ws_size,
                              hipStream_t stream) {
    const float* pred = (const float*)d_in[0];
    const float* tgt  = (const float*)d_in[1];
    float* out = (float*)d_out;
    unsigned short* ws16 = (unsigned short*)d_ws;  // 4 u16 volumes = 33.6 MB

    hipMemsetAsync(out, 0, sizeof(float), stream); // graph-capturable memset node
    zy_kernel<<<dim3(1024), 512, 0, stream>>>(pred, tgt, ws16);
    xloss_kernel<<<dim3(1024), 512, 0, stream>>>(pred, tgt, ws16, out);
}

// Round 9
// 149.490 us; speedup vs baseline: 1.2780x; 1.0088x over previous
//
#include <hip/hip_runtime.h>

// HausdorffDTLoss: exact separable EDT (fg & bg) per image, then
// mean((pred-target)^2 * (pred_dt^2 + target_dt^2)).
// Envelope identity: g[i] = min_j f[j]+(i-j)^2 = i^2 + min_j (h[j]-2ij),
// h[j]=f[j]+j^2. All intermediates are integers, |val| < 2^17 -> u16 storage,
// fp32 math exact (R1-R17: absmax 0.0).
// R12 windowing: scan only |i-j| <= W, W = ceil(sqrt(max f over outputs)) --
// exact for any input (j=i in-window; outside candidates >= f(i) >= g(i)).
//
// R18. R17: 150.8us, zy 57us, xloss <56us -> kernel-sum ~110us, so ~40us is
// inter-node gap overhead (2 gaps x ~20us). R16 showed hipLaunchCooperative
// fails under graph capture. Fix: fuse zy+xloss into ONE dispatch with a
// manual device-wide ticket barrier. 1024 blocks x 512thr at 4/CU x 256 CU
// are exactly co-resident (35.7KB LDS -> 4.48/CU; VGPR<=64); runtime
// occupancy guard (cap>=4) else fall back to the 2-dispatch path. Barrier:
// syncthreads -> threadfence (agent: L2 wb, cross-XCD visibility) -> t0
// atomicAdd+spin to 1024 (clock64 timeout ~40ms: breaks => wrong absmax,
// not a hung container) -> syncthreads -> threadfence (inv/acquire).
// Counter memset per launch (4B node); out zeroed by block 0 pre-barrier.
// Kernel bodies identical to R17 (proven).

constexpr int BIGI = 49153;      // 3*128^2+1, matches reference BIG exactly
constexpr int NVOX = 4194304;    // voxels per tensor (2 samples x 128^3)
constexpr int STZ  = 129;        // zy dword row stride: 129%32=1 -> 2-way max (free)
constexpr int STX  = 65;         // xloss dword row stride: 65%32=1 -> same property
constexpr int LDSW = 512 + 65 * STZ;   // bm(256 u64 = 512 w) + hz(65*129 w) = 35.6KB

// Windowed pair-packed lower-envelope into acc[16] at outputs i0..i0+15.
// p = column c of a [65*stride] u32 LDS array of packed u16 h-values
// (row 64 = slack for the 1-ahead prefetch). R14 proven form.
__device__ __forceinline__ void envelope_win(const unsigned int* __restrict__ p,
                                             const int stride, const float i0f,
                                             const int qlo, const int qhi,
                                             float acc[16]) {
    unsigned int vc = p[qlo * stride];
    float jm2 = -4.0f * (float)qlo;            // -2*(2q)
    for (int q = qlo; q <= qhi; ++q) {
        unsigned int vn = p[(q + 1) * stride]; // 1-pair prefetch (slack row)
        float h0 = (float)(vc & 0xffffu);      // j = 2q
        float h1 = (float)(vc >> 16);          // j = 2q+1
        float jb = jm2 - 2.0f;
        float c0 = fmaf(jm2, i0f, h0);         // candidate at i = i0
        float c1 = fmaf(jb,  i0f, h1);
#pragma unroll
        for (int k = 0; k < 16; ++k) {
            acc[k] = fminf(acc[k], fminf(c0, c1));
            c0 += jm2; c1 += jb;               // exact: integers < 2^17
        }
        jm2 -= 4.0f;
        vc = vn;
    }
}

// Wave-uniform window W from the wave's 16 output rows' f-values (pair-packed
// layout; f = h - i^2), wave-maxed. Guarantees W*W >= fmax.
__device__ __forceinline__ int window_of(const unsigned int* __restrict__ p,
                                         const int stride, const int i0) {
    int fmx = 0;
#pragma unroll
    for (int m = 0; m < 8; ++m) {
        unsigned int v = p[((i0 >> 1) + m) * stride];
        int y0 = i0 + 2 * m, y1 = y0 + 1;
        int f0 = (int)(v & 0xffffu) - y0 * y0;
        int f1 = (int)(v >> 16) - y1 * y1;
        fmx = max(fmx, max(f0, f1));
    }
#pragma unroll
    for (int off = 32; off; off >>= 1) fmx = max(fmx, __shfl_xor(fmx, off));
    int W = (int)sqrtf((float)fmx);            // fmx <= 49153, exact in fp32
    W += (W * W < fmx);
    W += (W * W < fmx);                        // guarantees W*W >= fmx
    return W;
}

// ---- zy phase body (R17 proven): binarize + bitmask z-EDT + y-envelope ----
// One (b,x) slab, one image, one polarity per block t. Stores g + x^2 (u16).
__device__ __forceinline__ void zy_body(const float* __restrict__ pred,
                                        const float* __restrict__ tgt,
                                        unsigned short* __restrict__ ws,
                                        unsigned int* lds, const int t) {
    unsigned long long* bm = (unsigned long long*)lds;   // 256 u64 site masks
    unsigned int* hz = lds + 512;                        // 65*STZ packed pairs
    const int pol = t & 1;                         // 0: fg EDT (sites=~fg), 1: bg
    const int img = (t >> 1) & 1;
    const int s   = t >> 2;                        // 0..255: b(2) x x(128)
    const int b   = s >> 7;
    const int x   = s & 127;
    const int sb  = (b * 128 + x) * 16384;         // + y*128 + z
    const int tid = threadIdx.x;
    const float* im = img ? tgt : pred;

    // stage phase 1: batch ALL 32 slab loads (two-phase, proven R14/R17)
    float vreg[32];
#pragma unroll
    for (int k = 0; k < 32; ++k) vreg[k] = im[sb + tid + k * 512];

    // stage phase 2: ballots -> site bitmasks
#pragma unroll
    for (int k = 0; k < 32; ++k) {
        bool fg = vreg[k] > 0.5f;
        bool site = pol ? fg : !fg;
        unsigned long long bal = __ballot(site);
        if ((tid & 63) == 0) bm[(tid + k * 512) >> 6] = bal; // uniform per wave
    }
    __syncthreads();

    // parallel z-EDT: per-voxel nearest-site distance from the masks
    unsigned short* hu = (unsigned short*)hz;
    const int z = tid & 127;                       // fixed per thread, uniform/wave
#pragma unroll
    for (int k = 0; k < 32; ++k) {
        int y = (tid >> 7) + k * 4;
        unsigned long long m0 = bm[2 * y], m1 = bm[2 * y + 1];
        int d;
        if (z < 64) {
            unsigned long long lm = m0 << (63 - z);
            unsigned long long rm = m0 >> z;
            int dfwd = lm ? __builtin_clzll(lm) : 999;
            int db0  = rm ? __builtin_ctzll(rm) : 999;
            int db1  = (m1 ? __builtin_ctzll(m1) : 999) + (64 - z);
            d = min(dfwd, min(db0, db1));
        } else {
            int zz = z - 64;
            unsigned long long lm = m1 << (63 - zz);
            unsigned long long rm = m1 >> zz;
            int df1 = lm ? __builtin_clzll(lm) : 999;
            int df0 = (m0 ? __builtin_clzll(m0) : 999) + zz + 1;
            int dbw = rm ? __builtin_ctzll(rm) : 999;
            d = min(min(df1, df0), dbw);
        }
        int f = (d <= 127) ? d * d : BIGI;         // empty line -> BIG (exact)
        hu[((y >> 1) * STZ) * 2 + (y & 1) + 2 * z] = (unsigned short)(f + y * y);
    }
    __syncthreads();

    // y-envelope: c = z column, 4 groups x 2 rounds; store g + x^2 (u16)
    unsigned short* outv = ws + (size_t)(img * 2 + pol) * NVOX + sb;
    const int c = tid & 127;
    const int xsq = x * x;
#pragma clang loop unroll(disable)
    for (int r = 0; r < 2; ++r) {                  // one acc[16] live at a time
        const int i0 = (tid >> 7) * 16 + r * 64;   // wave-uniform (tid>>7)
        const float i0f = (float)i0;
        const int W = window_of(hz + c, STZ, i0);
        const int qlo = __builtin_amdgcn_readfirstlane(max(0, (i0 - W) >> 1));
        const int qhi = __builtin_amdgcn_readfirstlane(min(63, (i0 + 15 + W) >> 1));
        float acc[16];
#pragma unroll
        for (int k = 0; k < 16; ++k) acc[k] = 3.0e38f;
        envelope_win(hz + c, STZ, i0f, qlo, qhi, acc);
#pragma unroll
        for (int k = 0; k < 16; ++k) {             // g + x^2 <= 65282: u16
            float iif = i0f + (float)k;
            outv[(i0 + k) * 128 + c] =
                (unsigned short)((unsigned int)fmaf(iif, iif, acc[k]) + xsq);
        }
    }
}

// ---- xloss phase body (R17 proven): dual-polarity x-envelope + loss ----
__device__ __forceinline__ void xloss_body(const float* __restrict__ pred,
                                           const float* __restrict__ tgt,
                                           const unsigned short* __restrict__ ws,
                                           float* __restrict__ out,
                                           unsigned int* hx, float* red,
                                           const int t) {
    const int img  = t & 1;                    // adjacent blocks share pred/tgt
    const int b    = (t >> 1) & 1;
    const int q0   = (t >> 2) * 64;            // (y,z) tile base, 0..16320
    const int base = b * 2097152 + q0;         // + x*16384 + c
    const int tid  = threadIdx.x;
    const int c    = tid & 63;
    const int i0   = (tid >> 6) * 16;          // wave-uniform (64 lanes = 64 cols)
    const float i0f = (float)i0;
    const unsigned short* A16 = ws + (size_t)(img * 2) * NVOX;
    const unsigned int* A32 = (const unsigned int*)(A16 + base);       // base even
    const unsigned int* B32 = (const unsigned int*)(A16 + NVOX + base);

    // hoisted scattered pred/tgt loads: latency hides under the scan
    float dv[16];
#pragma unroll
    for (int k = 0; k < 16; ++k) {
        int v = base + (i0 + k) * 16384 + c;   // 256B contiguous per wave
        dv[k] = pred[v] - tgt[v];
    }

    // stage BOTH volumes, u32 in AND out: word[j][c] = hA | hB<<16
#pragma unroll
    for (int k = 0; k < 8; ++k) {
        int l = tid + k * 512;                 // 0..4095
        int j = l >> 5, cp = l & 31;           // row j, u32 col-pair (c=2cp,2cp+1)
        unsigned int va = A32[j * 8192 + cp];
        unsigned int vb = B32[j * 8192 + cp];
        int w0 = j * STX + 2 * cp;
        hx[w0]     = (va & 0xffffu) | (vb << 16);          // col 2cp
        hx[w0 + 1] = (va >> 16)    | (vb & 0xffff0000u);   // col 2cp+1
    }
    __syncthreads();

    // window over both polarities + no-fg guard from fmxB
    const unsigned int* p = hx + c;
    int fmxA = 0, fmxB = 0;
#pragma unroll
    for (int m = 0; m < 16; ++m) {
        int j = i0 + m;
        unsigned int w = p[j * STX];
        fmxA = max(fmxA, (int)(w & 0xffffu) - j * j);  // f = h - j^2 >= 0
        fmxB = max(fmxB, (int)(w >> 16) - j * j);
    }
    int fmx = max(fmxA, fmxB);
#pragma unroll
    for (int off = 32; off; off >>= 1) {
        fmx  = max(fmx,  __shfl_xor(fmx,  off));
        fmxB = max(fmxB, __shfl_xor(fmxB, off));
    }
    int W = (int)sqrtf((float)fmx);
    W += (W * W < fmx);
    W += (W * W < fmx);                        // W*W >= fmx
    const int jlo = __builtin_amdgcn_readfirstlane(max(0, i0 - W));
    const int jhi = __builtin_amdgcn_readfirstlane(min(127, i0 + 15 + W));
    // bg-EDT f == BIGI uniformly iff sample has no fg (else <= 48387 < BIGI)
    const bool nofg = (fmxB >= BIGI);

    // fused scan: accA (pol0) + accB (pol1) in one pass, 1-ahead
    float accA[16], accB[16];
#pragma unroll
    for (int k = 0; k < 16; ++k) { accA[k] = 3.0e38f; accB[k] = 3.0e38f; }
    unsigned int vc = p[jlo * STX];
    float jm = -2.0f * (float)jlo;
    for (int j = jlo; j <= jhi; ++j) {
        unsigned int vn = p[(j + 1) * STX];    // row 128 slack exists
        float hA = (float)(vc & 0xffffu);
        float hB = (float)(vc >> 16);
        float cA = fmaf(jm, i0f, hA);          // candidate at i = i0
        float cB = fmaf(jm, i0f, hB);
#pragma unroll
        for (int k = 0; k < 16; ++k) {
            accA[k] = fminf(accA[k], cA);
            accB[k] = fminf(accB[k], cB);
            cA += jm; cB += jm;                // exact: integers < 2^17
        }
        jm -= 2.0f;
        vc = vn;
    }

    // loss partial: (p-t)^2 * (sqrt(gA)+sqrt(gB))^2 * guard
    // (sqrt-then-square kept: reference computes (sqrt g)**2, bit-compat)
    float s = 0.0f;
#pragma unroll
    for (int k = 0; k < 16; ++k) {
        float iif = i0f + (float)k;
        float gA = fmaf(iif, iif, accA[k]);
        float gB = fmaf(iif, iif, accB[k]);
        float d = dv[k];
        float fld = sqrtf(gA) + sqrtf(gB);
        s += d * d * fld * fld;
    }
    if (nofg) s = 0.0f;
#pragma unroll
    for (int off = 32; off > 0; off >>= 1) s += __shfl_down(s, off);
    if ((tid & 63) == 0) red[tid >> 6] = s;
    __syncthreads();
    if (tid == 0) {
        float tot = 0.0f;
#pragma unroll
        for (int w = 0; w < 8; ++w) tot += red[w];
        atomicAdd(out, tot * (1.0f / 4194304.0f));
    }
}

// ---- fused kernel: zy -> manual grid barrier -> xloss ----
__global__ __launch_bounds__(512) void fused_kernel(const float* __restrict__ pred,
                                                    const float* __restrict__ tgt,
                                                    unsigned short* __restrict__ ws,
                                                    unsigned int* __restrict__ bar,
                                                    float* __restrict__ out) {
    __shared__ __align__(16) unsigned int lds[LDSW];   // 35.6KB -> 4 blocks/CU
    __shared__ float red[8];
    const int t = blockIdx.x;
    if (t == 0 && threadIdx.x == 0) out[0] = 0.0f;     // release-ordered below

    zy_body(pred, tgt, ws, lds, t);

    // device-wide ticket barrier: all 1024 blocks co-resident (4/CU x 256CU,
    // guaranteed by host-side occupancy guard). Agent fences give cross-XCD
    // visibility of ws (L2 writeback on release, invalidate on acquire).
    __syncthreads();
    __threadfence();
    if (threadIdx.x == 0) {
        __hip_atomic_fetch_add(bar, 1u, __ATOMIC_RELEASE, __HIP_MEMORY_SCOPE_AGENT);
        long long t0 = clock64();
        while (__hip_atomic_load(bar, __ATOMIC_ACQUIRE, __HIP_MEMORY_SCOPE_AGENT)
               < 1024u) {
            __builtin_amdgcn_s_sleep(8);
            if (clock64() - t0 > 100000000LL) break;   // ~40ms: fail loud, not hung
        }
    }
    __syncthreads();
    __threadfence();

    xloss_body(pred, tgt, ws, out, lds, red, t);
}

// ---- fallback path: proven 2-dispatch pipeline (no memset: zy zeroes out) --
__global__ __launch_bounds__(512) void zy_kernel(const float* __restrict__ pred,
                                                 const float* __restrict__ tgt,
                                                 unsigned short* __restrict__ ws,
                                                 float* __restrict__ out) {
    __shared__ __align__(16) unsigned int lds[LDSW];
    if (blockIdx.x == 0 && threadIdx.x == 0) out[0] = 0.0f;  // pre-xloss dispatch
    zy_body(pred, tgt, ws, lds, blockIdx.x);
}

__global__ __launch_bounds__(512) void xloss_kernel(const float* __restrict__ pred,
                                                    const float* __restrict__ tgt,
                                                    const unsigned short* __restrict__ ws,
                                                    float* __restrict__ out) {
    __shared__ __align__(16) unsigned int lds[LDSW];
    __shared__ float red[8];
    xloss_body(pred, tgt, ws, out, lds, red, blockIdx.x);
}

extern "C" void kernel_launch(void* const* d_in, const int* in_sizes, int n_in,
                              void* d_out, int out_size, void* d_ws, size_t ws_size,
                              hipStream_t stream) {
    const float* pred = (const float*)d_in[0];
    const float* tgt  = (const float*)d_in[1];
    float* out = (float*)d_out;
    unsigned short* ws16 = (unsigned short*)d_ws;      // 4 u16 volumes = 33.6 MB
    unsigned int* bar = (unsigned int*)(ws16 + 4 * (size_t)NVOX);

    static int cap = -1;                               // cached occupancy query
    if (cap < 0) {
        if (hipOccupancyMaxActiveBlocksPerMultiprocessor(
                &cap, reinterpret_cast<const void*>(fused_kernel), 512, 0)
            != hipSuccess) cap = 0;
    }
    if (cap >= 4) {                                    // 4/CU x 256 CU >= 1024
        hipMemsetAsync(bar, 0, sizeof(unsigned int), stream);
        fused_kernel<<<dim3(1024), 512, 0, stream>>>(pred, tgt, ws16, bar, out);
    } else {
        zy_kernel<<<dim3(1024), 512, 0, stream>>>(pred, tgt, ws16, out);
        xloss_kernel<<<dim3(1024), 512, 0, stream>>>(pred, tgt, ws16, out);
    }
}